// Round 21
// baseline (242.595 us; speedup 1.0000x reference)
//
#include <hip/hip_runtime.h>

#define DD 64
#define TT 8192
#define KK 2048
#define NTROWS 65536
#define TAUF 0.015f

// d_out layout (float offsets), matching reference return order:
// xd[8*64*8192] | codes[65536] | commit[1] | k_new[131072] | k_sum_n[131072] | k_elem_n[2048]
#define OFF_CODES  4194304ull
#define OFF_COMMIT 4259840ull
#define OFF_KNEW   4259841ull
#define OFF_KSUM   4390913ull
#define OFF_KELEM  4521985ull

#define SQ(a) __fmul_rn((a), (a))

typedef short bf16x8 __attribute__((ext_vector_type(8)));
typedef float f32x4 __attribute__((ext_vector_type(4)));
typedef unsigned short ushort_t;

__device__ __forceinline__ ushort_t f2bf(float f) {
  unsigned u = __float_as_uint(f);
  unsigned r = u + 0x7fffu + ((u >> 16) & 1u);
  return (ushort_t)(r >> 16);
}
__device__ __forceinline__ float bf2f(ushort_t s) {
  return __uint_as_float(((unsigned)s) << 16);
}

// ---------------- prep: sk[c] = np.sum(k[c]*k[c]) in replicated fp32 ----------
__global__ __launch_bounds__(256) void vq_prep(const float* __restrict__ k,
                                               float* __restrict__ sk) {
  int c = blockIdx.x * 256 + threadIdx.x;
  if (c < KK) {
    const float* v = k + (size_t)c * DD;
    float r[8];
#pragma unroll
    for (int j = 0; j < 8; ++j) r[j] = SQ(v[j]);
#pragma unroll
    for (int i = 8; i < 64; i += 8) {
#pragma unroll
      for (int j = 0; j < 8; ++j) r[j] = __fadd_rn(r[j], SQ(v[i + j]));
    }
    sk[c] = __fadd_rn(
        __fadd_rn(__fadd_rn(r[0], r[1]), __fadd_rn(r[2], r[3])),
        __fadd_rn(__fadd_rn(r[4], r[5]), __fadd_rn(r[6], r[7])));
  }
}

// ---------------- kprep: bf16 split of k (hi + lo) ----------------
__global__ __launch_bounds__(256) void vq_kprep(const float* __restrict__ k,
                                                ushort_t* __restrict__ kbh,
                                                ushort_t* __restrict__ kbl) {
  const int i = blockIdx.x * 256 + threadIdx.x;  // 0..131071
  const float v = k[i];
  const ushort_t h = f2bf(v);
  kbh[i] = h;
  kbl[i] = f2bf(__fsub_rn(v, bf2f(h)));
}

// ---------------- argmin via MFMA filter: 2 waves/block, 4 M-tiles/wave ------
// r17/r20 counters: LDS-read is the top pipe (8 waves x 16 ds_read_b128 x
// 12cyc = 1536 cyc/CU-iter vs MFMA 466). Same 128-row block + B-panel
// double-buffer + 2-barrier structure, but 2 waves x 4 M-tiles: the same 16
// B-fragment reads/iter now feed 96 MFMA and 64 rows per wave -> LDS and
// staging cost per row halve. waves_per_eu(1,1): 1 wave/SIMD (1024 waves
// total), full register budget (A-frags 64 + track 48 VGPRs, no spill).
// Per-(row,code) arithmetic identical to the r12-validated filter.
__global__ __launch_bounds__(128)
__attribute__((amdgpu_waves_per_eu(1, 1)))
void vq_argmin_mfma(
    const float* __restrict__ x, const ushort_t* __restrict__ kbh,
    const ushort_t* __restrict__ kbl, const float* __restrict__ sk,
    float* __restrict__ out_codes, float* __restrict__ xf,
    int* __restrict__ susp_cnt, int* __restrict__ susp_rows) {
  __shared__ float xs[128][68];       // 34816 B
  __shared__ ushort_t Bl[2][8192];    // 2 x 16 KB B panels (4 tiles each)
  __shared__ int slist[128];
  __shared__ int scnt, sbase;

  const int tid = threadIdx.x;        // 0..127
  const int lane = tid & 63;
  const int w = tid >> 6;             // 0..1 (hi- or lo-split stager)
  const int g = lane >> 4;
  const int c16 = lane & 15;
  const int R0 = blockIdx.x * 128;
  const int n = R0 >> 13;
  const int t0 = R0 & (TT - 1);

  if (tid == 0) scnt = 0;

  // ---- stage 128 rows into LDS (coalesced over t) ----
  {
    const float* xb = x + (size_t)n * (DD * TT) + t0;
#pragma unroll
    for (int d = 0; d < 64; ++d) xs[tid][d] = xb[(size_t)d * TT + tid];
  }

  // ---- per-thread B staging bases: thread (w,c16,g) stages fragment slots
  // {2w, 2w+1} = (kbsel = w?lo:hi) x (kch 0,1) for all 4 tiles ----
  const ushort_t* kbsel = w ? kbl : kbh;
  const ushort_t* bqA0 = kbsel + ((size_t)(0 * 16 + c16) * 64 + 0 * 32 + g * 8);
  const ushort_t* bqA1 = kbsel + ((size_t)(0 * 16 + c16) * 64 + 1 * 32 + g * 8);
  const ushort_t* bqB0 = kbsel + ((size_t)(1 * 16 + c16) * 64 + 0 * 32 + g * 8);
  const ushort_t* bqB1 = kbsel + ((size_t)(1 * 16 + c16) * 64 + 1 * 32 + g * 8);
  const ushort_t* bqC0 = kbsel + ((size_t)(2 * 16 + c16) * 64 + 0 * 32 + g * 8);
  const ushort_t* bqC1 = kbsel + ((size_t)(2 * 16 + c16) * 64 + 1 * 32 + g * 8);
  const ushort_t* bqD0 = kbsel + ((size_t)(3 * 16 + c16) * 64 + 0 * 32 + g * 8);
  const ushort_t* bqD1 = kbsel + ((size_t)(3 * 16 + c16) * 64 + 1 * 32 + g * 8);

  // prologue: load + write phase 0 (slot = (2w+kc)*64 + lane within tile)
  {
    int4 rA0 = *(const int4*)bqA0, rA1 = *(const int4*)bqA1;
    int4 rB0 = *(const int4*)bqB0, rB1 = *(const int4*)bqB1;
    int4 rC0 = *(const int4*)bqC0, rC1 = *(const int4*)bqC1;
    int4 rD0 = *(const int4*)bqD0, rD1 = *(const int4*)bqD1;
    *(int4*)&Bl[0][(0 * 256 + (2 * w + 0) * 64 + lane) * 8] = rA0;
    *(int4*)&Bl[0][(0 * 256 + (2 * w + 1) * 64 + lane) * 8] = rA1;
    *(int4*)&Bl[0][(1 * 256 + (2 * w + 0) * 64 + lane) * 8] = rB0;
    *(int4*)&Bl[0][(1 * 256 + (2 * w + 1) * 64 + lane) * 8] = rB1;
    *(int4*)&Bl[0][(2 * 256 + (2 * w + 0) * 64 + lane) * 8] = rC0;
    *(int4*)&Bl[0][(2 * 256 + (2 * w + 1) * 64 + lane) * 8] = rC1;
    *(int4*)&Bl[0][(3 * 256 + (2 * w + 0) * 64 + lane) * 8] = rD0;
    *(int4*)&Bl[0][(3 * 256 + (2 * w + 1) * 64 + lane) * 8] = rD1;
  }
  __syncthreads();  // xs + phase-0 panel ready

  // ---- emit xf[row][d] transpose (for codesum + rescue); thread = row ----
  {
    float4* dst = (float4*)(xf + (size_t)(R0 + tid) * DD);
#pragma unroll
    for (int j = 0; j < 16; ++j) {
      dst[j] = make_float4(xs[tid][4 * j], xs[tid][4 * j + 1],
                           xs[tid][4 * j + 2], xs[tid][4 * j + 3]);
    }
  }

  // ---- A-frag prep: wave w owns rows w*64 + M*16 + c16, M=0..3 ----
  union FR { bf16x8 v; ushort_t u[8]; };
  bf16x8 AH00, AH01, AH10, AH11, AH20, AH21, AH30, AH31;
  bf16x8 AL00, AL01, AL10, AL11, AL20, AL21, AL30, AL31;
#define CVT(J, VAL)                                   \
  { const float fv = (VAL); const ushort_t hb = f2bf(fv); \
    hh.u[J] = hb; ll.u[J] = f2bf(__fsub_rn(fv, bf2f(hb))); }
#define APREP(M, C, HN, LN)                            \
  { const int rowl = w * 64 + (M)*16 + c16;            \
    const int d0 = (C)*32 + g * 8;                     \
    const float4 v0 = *(const float4*)&xs[rowl][d0];   \
    const float4 v1 = *(const float4*)&xs[rowl][d0 + 4]; \
    FR hh, ll;                                         \
    CVT(0, v0.x) CVT(1, v0.y) CVT(2, v0.z) CVT(3, v0.w) \
    CVT(4, v1.x) CVT(5, v1.y) CVT(6, v1.z) CVT(7, v1.w) \
    HN = hh.v; LN = ll.v; }
  APREP(0, 0, AH00, AL00) APREP(0, 1, AH01, AL01)
  APREP(1, 0, AH10, AL10) APREP(1, 1, AH11, AL11)
  APREP(2, 0, AH20, AL20) APREP(2, 1, AH21, AL21)
  APREP(3, 0, AH30, AL30) APREP(3, 1, AH31, AL31)

  const float FMAXV = 3.402823466e38f;
  float m1_0 = FMAXV, m1_1 = FMAXV, m1_2 = FMAXV, m1_3 = FMAXV;
  float m1_4 = FMAXV, m1_5 = FMAXV, m1_6 = FMAXV, m1_7 = FMAXV;
  float m1_8 = FMAXV, m1_9 = FMAXV, m1_10 = FMAXV, m1_11 = FMAXV;
  float m1_12 = FMAXV, m1_13 = FMAXV, m1_14 = FMAXV, m1_15 = FMAXV;
  float m2_0 = FMAXV, m2_1 = FMAXV, m2_2 = FMAXV, m2_3 = FMAXV;
  float m2_4 = FMAXV, m2_5 = FMAXV, m2_6 = FMAXV, m2_7 = FMAXV;
  float m2_8 = FMAXV, m2_9 = FMAXV, m2_10 = FMAXV, m2_11 = FMAXV;
  float m2_12 = FMAXV, m2_13 = FMAXV, m2_14 = FMAXV, m2_15 = FMAXV;
  int i1_0 = 0, i1_1 = 0, i1_2 = 0, i1_3 = 0;
  int i1_4 = 0, i1_5 = 0, i1_6 = 0, i1_7 = 0;
  int i1_8 = 0, i1_9 = 0, i1_10 = 0, i1_11 = 0;
  int i1_12 = 0, i1_13 = 0, i1_14 = 0, i1_15 = 0;

#define TRACK(S, V)                                                   \
  { const float dd = fmaf(-2.0f, (V), skc);                           \
    const bool lt = dd < m1_##S;                                      \
    m2_##S = fminf(m2_##S, lt ? m1_##S : dd);                         \
    m1_##S = lt ? dd : m1_##S;                                        \
    i1_##S = lt ? codeIdx : i1_##S; }

#define MFMA(A, B, C) __builtin_amdgcn_mfma_f32_16x16x32_bf16((A), (B), (C), 0, 0, 0)

#define TILE(TT_)                                                              \
  {                                                                            \
    const int codeBase = p * 64 + (TT_)*16;                                    \
    const bf16x8 bh0 = *(const bf16x8*)&Bl[pb][((TT_)*256 + 0 * 64 + lane) * 8]; \
    const bf16x8 bh1 = *(const bf16x8*)&Bl[pb][((TT_)*256 + 1 * 64 + lane) * 8]; \
    const bf16x8 bl0 = *(const bf16x8*)&Bl[pb][((TT_)*256 + 2 * 64 + lane) * 8]; \
    const bf16x8 bl1 = *(const bf16x8*)&Bl[pb][((TT_)*256 + 3 * 64 + lane) * 8]; \
    f32x4 a0 = {0.f, 0.f, 0.f, 0.f}, a1 = {0.f, 0.f, 0.f, 0.f};                \
    f32x4 a2 = {0.f, 0.f, 0.f, 0.f}, a3 = {0.f, 0.f, 0.f, 0.f};                \
    a0 = MFMA(AH00, bh0, a0); a1 = MFMA(AH10, bh0, a1);                        \
    a2 = MFMA(AH20, bh0, a2); a3 = MFMA(AH30, bh0, a3);                        \
    a0 = MFMA(AH01, bh1, a0); a1 = MFMA(AH11, bh1, a1);                        \
    a2 = MFMA(AH21, bh1, a2); a3 = MFMA(AH31, bh1, a3);                        \
    a0 = MFMA(AH00, bl0, a0); a1 = MFMA(AH10, bl0, a1);                        \
    a2 = MFMA(AH20, bl0, a2); a3 = MFMA(AH30, bl0, a3);                        \
    a0 = MFMA(AH01, bl1, a0); a1 = MFMA(AH11, bl1, a1);                        \
    a2 = MFMA(AH21, bl1, a2); a3 = MFMA(AH31, bl1, a3);                        \
    a0 = MFMA(AL00, bh0, a0); a1 = MFMA(AL10, bh0, a1);                        \
    a2 = MFMA(AL20, bh0, a2); a3 = MFMA(AL30, bh0, a3);                        \
    a0 = MFMA(AL01, bh1, a0); a1 = MFMA(AL11, bh1, a1);                        \
    a2 = MFMA(AL21, bh1, a2); a3 = MFMA(AL31, bh1, a3);                        \
    const float skc = sk[codeBase + c16];                                      \
    const int codeIdx = codeBase + c16;                                        \
    TRACK(0, a0[0]) TRACK(1, a0[1]) TRACK(2, a0[2]) TRACK(3, a0[3])            \
    TRACK(4, a1[0]) TRACK(5, a1[1]) TRACK(6, a1[2]) TRACK(7, a1[3])            \
    TRACK(8, a2[0]) TRACK(9, a2[1]) TRACK(10, a2[2]) TRACK(11, a2[3])          \
    TRACK(12, a3[0]) TRACK(13, a3[1]) TRACK(14, a3[2]) TRACK(15, a3[3])        \
  }

  int4 rA0, rA1, rB0, rB1, rC0, rC1, rD0, rD1;
  for (int p = 0; p < 32; ++p) {
    const int pb = p & 1;
    if (p < 31) {  // issue next-panel loads (hide under MFMA)
      const size_t off = (size_t)(p + 1) * 4096;
      rA0 = *(const int4*)(bqA0 + off); rA1 = *(const int4*)(bqA1 + off);
      rB0 = *(const int4*)(bqB0 + off); rB1 = *(const int4*)(bqB1 + off);
      rC0 = *(const int4*)(bqC0 + off); rC1 = *(const int4*)(bqC1 + off);
      rD0 = *(const int4*)(bqD0 + off); rD1 = *(const int4*)(bqD1 + off);
    }
    TILE(0) TILE(1) TILE(2) TILE(3)
    __syncthreads();
    if (p < 31) {
      const int nb = pb ^ 1;
      *(int4*)&Bl[nb][(0 * 256 + (2 * w + 0) * 64 + lane) * 8] = rA0;
      *(int4*)&Bl[nb][(0 * 256 + (2 * w + 1) * 64 + lane) * 8] = rA1;
      *(int4*)&Bl[nb][(1 * 256 + (2 * w + 0) * 64 + lane) * 8] = rB0;
      *(int4*)&Bl[nb][(1 * 256 + (2 * w + 1) * 64 + lane) * 8] = rB1;
      *(int4*)&Bl[nb][(2 * 256 + (2 * w + 0) * 64 + lane) * 8] = rC0;
      *(int4*)&Bl[nb][(2 * 256 + (2 * w + 1) * 64 + lane) * 8] = rC1;
      *(int4*)&Bl[nb][(3 * 256 + (2 * w + 0) * 64 + lane) * 8] = rD0;
      *(int4*)&Bl[nb][(3 * 256 + (2 * w + 1) * 64 + lane) * 8] = rD1;
    }
    __syncthreads();
  }

  // ---- reduce across the 16 lanes of each lanegroup (codes) ----
#define REDSTEP(S, MASK)                                              \
  { const float o1 = __shfl_xor(m1_##S, MASK);                        \
    const int oi = __shfl_xor(i1_##S, MASK);                          \
    const float o2 = __shfl_xor(m2_##S, MASK);                        \
    const float hi2 = fmaxf(m1_##S, o1);                              \
    m2_##S = fminf(fminf(m2_##S, o2), hi2);                           \
    const bool tk = (o1 < m1_##S) || (o1 == m1_##S && oi < i1_##S);   \
    m1_##S = tk ? o1 : m1_##S;                                        \
    i1_##S = tk ? oi : i1_##S; }
#define RED(S) REDSTEP(S, 1) REDSTEP(S, 2) REDSTEP(S, 4) REDSTEP(S, 8)
  RED(0) RED(1) RED(2) RED(3) RED(4) RED(5) RED(6) RED(7)
  RED(8) RED(9) RED(10) RED(11) RED(12) RED(13) RED(14) RED(15)

  if (c16 == 0) {
#define WOUT(S, M, I)                                                   \
    { const int row = R0 + w * 64 + (M)*16 + g * 4 + (I);               \
      out_codes[row] = (float)i1_##S;                                   \
      if (m2_##S - m1_##S < TAUF) {                                     \
        const int pos = atomicAdd(&scnt, 1); slist[pos] = row; } }
    WOUT(0, 0, 0) WOUT(1, 0, 1) WOUT(2, 0, 2) WOUT(3, 0, 3)
    WOUT(4, 1, 0) WOUT(5, 1, 1) WOUT(6, 1, 2) WOUT(7, 1, 3)
    WOUT(8, 2, 0) WOUT(9, 2, 1) WOUT(10, 2, 2) WOUT(11, 2, 3)
    WOUT(12, 3, 0) WOUT(13, 3, 1) WOUT(14, 3, 2) WOUT(15, 3, 3)
  }
  __syncthreads();
  if (tid == 0 && scnt > 0) sbase = atomicAdd(susp_cnt, scnt);
  __syncthreads();
  for (int i = tid; i < scnt; i += 128) susp_rows[sbase + i] = slist[i];
}

// ---------------- rescue: one WAVE per suspect row (r16-validated) ----------
__global__ __launch_bounds__(256) void vq_rescue(
    const float* __restrict__ xf, const float* __restrict__ k,
    const float* __restrict__ sk, const int* __restrict__ susp_cnt,
    const int* __restrict__ susp_rows, float* __restrict__ out_codes) {
  __shared__ float xs[4][64];
  const int lane = threadIdx.x & 63;
  const int wv = threadIdx.x >> 6;
  const int nsusp = *susp_cnt;
  const int nit = (nsusp + 8191) >> 13;   // uniform trip count (8192 rows/pass)

  for (int it = 0; it < nit; ++it) {
    const int si = it * 8192 + blockIdx.x * 4 + wv;
    const bool act = si < nsusp;
    int row = 0;
    if (act) {
      row = susp_rows[si];
      xs[wv][lane] = xf[(size_t)row * DD + lane];   // coalesced
    }
    __syncthreads();

    if (act) {
      // np's ||x||^2 replica fold (broadcast LDS reads)
      float sumx;
      {
        float rr[8];
#pragma unroll
        for (int j = 0; j < 8; ++j) rr[j] = SQ(xs[wv][j]);
#pragma unroll
        for (int i = 8; i < 64; i += 8) {
#pragma unroll
          for (int j = 0; j < 8; ++j) rr[j] = __fadd_rn(rr[j], SQ(xs[wv][i + j]));
        }
        sumx = __fadd_rn(
            __fadd_rn(__fadd_rn(rr[0], rr[1]), __fadd_rn(rr[2], rr[3])),
            __fadd_rn(__fadd_rn(rr[4], rr[5]), __fadd_rn(rr[6], rr[7])));
      }

      float best = 3.402823466e38f;
      int bidx = lane;
#pragma unroll 4
      for (int i = 0; i < 32; ++i) {
        const int c = lane + i * 64;
        const float4* kp = (const float4*)(k + (size_t)c * DD);
        float a = 0.f;
#pragma unroll
        for (int j = 0; j < 16; ++j) {
          const float4 kv = kp[j];
          a = fmaf(xs[wv][4 * j + 0], kv.x, a);
          a = fmaf(xs[wv][4 * j + 1], kv.y, a);
          a = fmaf(xs[wv][4 * j + 2], kv.z, a);
          a = fmaf(xs[wv][4 * j + 3], kv.w, a);
        }
        const float dd = __fadd_rn(__fsub_rn(sumx, __fmul_rn(2.0f, a)), sk[c]);
        if (dd < best) { best = dd; bidx = c; }   // strict < -> first in-lane
      }

      // 64-lane butterfly, tie -> lowest index (np.argmin)
#pragma unroll
      for (int off = 1; off <= 32; off <<= 1) {
        const float ov = __shfl_xor(best, off);
        const int oi = __shfl_xor(bidx, off);
        if (ov < best || (ov == best && oi < bidx)) { best = ov; bidx = oi; }
      }
      if (lane == 0) out_codes[row] = (float)bidx;
    }
    __syncthreads();
  }
}

// ---------------- bucket build: count -> scan -> scatter packed entries -------
__global__ __launch_bounds__(256) void vq_count(const float* __restrict__ codes_f,
                                                int* __restrict__ cnt_int) {
  const int row = blockIdx.x * 256 + threadIdx.x;
  atomicAdd(&cnt_int[(int)codes_f[row]], 1);
}

__global__ __launch_bounds__(256) void vq_scan(const int* __restrict__ cnt_int,
                                               int* __restrict__ cursor) {
  __shared__ int sm[256];
  const int t = threadIdx.x;
  int v[8];
  int tot = 0;
#pragma unroll
  for (int j = 0; j < 8; ++j) { v[j] = cnt_int[t * 8 + j]; tot += v[j]; }
  sm[t] = tot;
  __syncthreads();
  int val = tot;
  for (int off = 1; off < 256; off <<= 1) {
    const int add = (t >= off) ? sm[t - off] : 0;
    __syncthreads();
    val += add;
    sm[t] = val;
    __syncthreads();
  }
  int base = val - tot;  // exclusive
#pragma unroll
  for (int j = 0; j < 8; ++j) { cursor[t * 8 + j] = base; base += v[j]; }
}

// bucket entry = (code << 16) | row  (code < 2048, row < 65536)
__global__ __launch_bounds__(256) void vq_scatteridx(
    const float* __restrict__ codes_f, int* __restrict__ cursor,
    unsigned* __restrict__ bucket) {
  const int row = blockIdx.x * 256 + threadIdx.x;
  const int code = (int)codes_f[row];
  const int pos = atomicAdd(&cursor[code], 1);
  bucket[pos] = ((unsigned)code << 16) | (unsigned)row;
}

// ---------------- segmented sum: uniform 64-entry chunks per wave ----------
__global__ __launch_bounds__(256) void vq_codesum(
    const float* __restrict__ xf, const unsigned* __restrict__ bucket,
    float* __restrict__ out_ksum) {
  __shared__ unsigned sh[4][64];
  const int lane = threadIdx.x & 63;   // d
  const int wv = threadIdx.x >> 6;
  const int base = (blockIdx.x * 4 + wv) * 64;

  sh[wv][lane] = bucket[base + lane];
  __syncthreads();

  float acc = 0.f;
  int cur = (int)(sh[wv][0] >> 16);
#pragma unroll
  for (int b = 0; b < 8; ++b) {
    float xv[8];
    int cd[8];
#pragma unroll
    for (int j = 0; j < 8; ++j) {
      const unsigned p = sh[wv][b * 8 + j];
      cd[j] = (int)(p >> 16);
      xv[j] = xf[(size_t)(p & 0xFFFFu) * DD + lane];   // coalesced 256B
    }
#pragma unroll
    for (int j = 0; j < 8; ++j) {
      if (cd[j] != cur) {            // wave-uniform branch
        atomicAdd(&out_ksum[(size_t)cur * DD + lane], acc);
        acc = 0.f;
        cur = cd[j];
      }
      acc = __fadd_rn(acc, xv[j]);
    }
  }
  atomicAdd(&out_ksum[(size_t)cur * DD + lane], acc);
}

// ---------------- epilogue: pure streaming (no atomics) ----------------
__global__ __launch_bounds__(256) void vq_epi(
    const float* __restrict__ x, const float* __restrict__ k,
    const float* __restrict__ codes_f, float* __restrict__ out_xd,
    float* __restrict__ partial) {
  const int lane = threadIdx.x & 63;
  const int q = threadIdx.x >> 6;
  const int row = blockIdx.x * 64 + lane;
  const int n = row >> 13;
  const int t = row & (TT - 1);
  const int d0 = blockIdx.y * 16 + q * 4;

  const int code = (int)codes_f[row];

  const float* xp = x + (size_t)n * (DD * TT) + t;
  float* xd_base = out_xd + (size_t)n * (DD * TT) + t;

  const float4 kq = ((const float4*)k)[(size_t)code * 16 + (d0 >> 2)];

  float csum = 0.f;
#pragma unroll
  for (int j = 0; j < 4; ++j) {
    const int d = d0 + j;
    const float xqv = (j == 0) ? kq.x : (j == 1) ? kq.y : (j == 2) ? kq.z : kq.w;
    const float xv = xp[(size_t)d * TT];
    const float diff = __fsub_rn(xqv, xv);
    xd_base[(size_t)d * TT] = __fadd_rn(xv, diff);
    csum = fmaf(diff, diff, csum);
  }

  __shared__ float cs[4];
#pragma unroll
  for (int off = 32; off >= 1; off >>= 1) csum += __shfl_xor(csum, off);
  if (lane == 0) cs[q] = csum;
  __syncthreads();
  if (threadIdx.x == 0) {
    partial[blockIdx.y * 1024 + blockIdx.x] = (cs[0] + cs[1]) + (cs[2] + cs[3]);
  }
}

// ---------------- finalize: commit reduce + EMA buffers + k_new ----------------
__global__ __launch_bounds__(256) void vq_finalize(
    const float* __restrict__ k, const float* __restrict__ k_sum,
    const float* __restrict__ k_elem, const int* __restrict__ cnt_int,
    const float* __restrict__ partial, float* __restrict__ out_commit,
    float* __restrict__ out_knew, float* __restrict__ out_ksum,
    float* __restrict__ out_kelem) {
  const int i = blockIdx.x * 256 + threadIdx.x;

  if (blockIdx.x == 0) {
    __shared__ float red[256];
    float s = 0.f;
#pragma unroll
    for (int j = 0; j < 16; ++j) s += partial[threadIdx.x * 16 + j];
    red[threadIdx.x] = s;
    __syncthreads();
    for (int off = 128; off >= 1; off >>= 1) {
      if (threadIdx.x < off) red[threadIdx.x] += red[threadIdx.x + off];
      __syncthreads();
    }
    if (threadIdx.x == 0) out_commit[0] = red[0] / 4194304.0f;
  }

  if (i < KK * DD) {
    const int c = i >> 6;
    const float cnt = (float)cnt_int[c];
    const float ke_n = __fadd_rn(__fmul_rn(0.99f, k_elem[c]), __fmul_rn(0.01f, cnt));
    const float s_raw = out_ksum[i];
    const float ks_n = __fadd_rn(__fmul_rn(0.99f, k_sum[i]), __fmul_rn(0.01f, s_raw));
    out_ksum[i] = ks_n;
    out_knew[i] = (ke_n >= 1.0f) ? (ks_n / ke_n) : k[i];
    if ((i & 63) == 0) out_kelem[c] = ke_n;
  }
}

extern "C" void kernel_launch(void* const* d_in, const int* in_sizes, int n_in,
                              void* d_out, int out_size, void* d_ws, size_t ws_size,
                              hipStream_t stream) {
  const float* x = (const float*)d_in[0];
  const float* k = (const float*)d_in[1];
  const float* k_sum = (const float*)d_in[2];
  const float* k_elem = (const float*)d_in[3];

  float* out = (float*)d_out;
  float* out_xd = out;                 // doubles as xf scratch until vq_epi
  float* out_codes = out + OFF_CODES;
  float* out_commit = out + OFF_COMMIT;
  float* out_knew = out + OFF_KNEW;
  float* out_ksum = out + OFF_KSUM;
  float* out_kelem = out + OFF_KELEM;

  // bf16-split k lives in the out_knew region (512 KB), 16B-aligned; the
  // <=12 B overhang into out_ksum is wiped by the out_ksum memset (enqueued
  // after argmin). knew itself is rewritten by vq_finalize at the very end.
  ushort_t* kbh = (ushort_t*)(((size_t)(out + OFF_KNEW) + 15) & ~(size_t)15);
  ushort_t* kbl = kbh + (size_t)KK * DD;

  char* ws = (char*)d_ws;
  float* sk = (float*)ws;                       // 8 KB
  int* cnt_int = (int*)(ws + 8192);             // 8 KB
  int* cursor = (int*)(ws + 16384);             // 8 KB
  float* partial = (float*)(ws + 24576);        // 16 KB
  unsigned* bucket = (unsigned*)(ws + 40960);   // 256 KB
  int* susp_cnt = cursor;                       // aliased: rescue precedes scan
  int* susp_rows = (int*)bucket;                // aliased: rescue precedes scatter

  hipMemsetAsync(cnt_int, 0, (size_t)KK * sizeof(int), stream);
  hipMemsetAsync(susp_cnt, 0, sizeof(int), stream);

  vq_prep<<<(KK + 255) / 256, 256, 0, stream>>>(k, sk);
  vq_kprep<<<(KK * DD) / 256, 256, 0, stream>>>(k, kbh, kbl);

  vq_argmin_mfma<<<NTROWS / 128, 128, 0, stream>>>(x, kbh, kbl, sk, out_codes,
                                                   out_xd, susp_cnt, susp_rows);

  // zero the atomic accumulation target (also wipes kbl's 12 B overhang)
  hipMemsetAsync(out_ksum, 0, (size_t)KK * DD * sizeof(float), stream);

  vq_rescue<<<2048, 256, 0, stream>>>(out_xd, k, sk, susp_cnt, susp_rows,
                                      out_codes);

  vq_count<<<NTROWS / 256, 256, 0, stream>>>(out_codes, cnt_int);
  vq_scan<<<1, 256, 0, stream>>>(cnt_int, cursor);
  vq_scatteridx<<<NTROWS / 256, 256, 0, stream>>>(out_codes, cursor, bucket);
  vq_codesum<<<NTROWS / 256, 256, 0, stream>>>(out_xd, bucket, out_ksum);

  dim3 epi_grid(NTROWS / 64, 4);
  vq_epi<<<epi_grid, 256, 0, stream>>>(x, k, out_codes, out_xd, partial);

  vq_finalize<<<(KK * DD + 255) / 256, 256, 0, stream>>>(
      k, k_sum, k_elem, cnt_int, partial, out_commit, out_knew, out_ksum,
      out_kelem);
}

// Round 22
// 195.814 us; speedup vs baseline: 1.2389x; 1.2389x over previous
//
#include <hip/hip_runtime.h>

#define DD 64
#define TT 8192
#define KK 2048
#define NTROWS 65536
#define TAUF 0.005f

// d_out layout (float offsets), matching reference return order:
// xd[8*64*8192] | codes[65536] | commit[1] | k_new[131072] | k_sum_n[131072] | k_elem_n[2048]
#define OFF_CODES  4194304ull
#define OFF_COMMIT 4259840ull
#define OFF_KNEW   4259841ull
#define OFF_KSUM   4390913ull
#define OFF_KELEM  4521985ull

#define SQ(a) __fmul_rn((a), (a))

typedef short bf16x8 __attribute__((ext_vector_type(8)));
typedef float f32x4 __attribute__((ext_vector_type(4)));
typedef unsigned short ushort_t;

__device__ __forceinline__ ushort_t f2bf(float f) {
  unsigned u = __float_as_uint(f);
  unsigned r = u + 0x7fffu + ((u >> 16) & 1u);
  return (ushort_t)(r >> 16);
}
__device__ __forceinline__ float bf2f(ushort_t s) {
  return __uint_as_float(((unsigned)s) << 16);
}

// ---------------- prep: sk[c] = np.sum(k[c]*k[c]) in replicated fp32 ----------
__global__ __launch_bounds__(256) void vq_prep(const float* __restrict__ k,
                                               float* __restrict__ sk) {
  int c = blockIdx.x * 256 + threadIdx.x;
  if (c < KK) {
    const float* v = k + (size_t)c * DD;
    float r[8];
#pragma unroll
    for (int j = 0; j < 8; ++j) r[j] = SQ(v[j]);
#pragma unroll
    for (int i = 8; i < 64; i += 8) {
#pragma unroll
      for (int j = 0; j < 8; ++j) r[j] = __fadd_rn(r[j], SQ(v[i + j]));
    }
    sk[c] = __fadd_rn(
        __fadd_rn(__fadd_rn(r[0], r[1]), __fadd_rn(r[2], r[3])),
        __fadd_rn(__fadd_rn(r[4], r[5]), __fadd_rn(r[6], r[7])));
  }
}

// ---------------- kprep: bf16 split of k (hi + lo) ----------------
__global__ __launch_bounds__(256) void vq_kprep(const float* __restrict__ k,
                                                ushort_t* __restrict__ kbh,
                                                ushort_t* __restrict__ kbl) {
  const int i = blockIdx.x * 256 + threadIdx.x;  // 0..131071
  const float v = k[i];
  const ushort_t h = f2bf(v);
  kbh[i] = h;
  kbl[i] = f2bf(__fsub_rn(v, bf2f(h)));
}

// ---------------- argmin via MFMA filter (r17-frozen structure) --------------
// r18 (occupancy), r19 (L2-stream), r20 (chain-split), r21 (wide M-tiles) all
// failed to beat this configuration -> structure frozen. Changes vs the
// 204-us r17 source: counts non-suspect rows into cnt_int (vq_count kernel
// removed; pattern validated in r18/r19).
__global__ __launch_bounds__(256)
__attribute__((amdgpu_waves_per_eu(2, 2)))
void vq_argmin_mfma(
    const float* __restrict__ x, const ushort_t* __restrict__ kbh,
    const ushort_t* __restrict__ kbl, const float* __restrict__ sk,
    float* __restrict__ out_codes, float* __restrict__ xf,
    int* __restrict__ susp_cnt, int* __restrict__ susp_rows,
    int* __restrict__ cnt_int) {
  __shared__ float xs[128][68];       // 34816 B
  __shared__ ushort_t Bl[2][8192];    // 2 x 16 KB B panels (4 tiles each)
  __shared__ int slist[128];
  __shared__ int scnt, sbase;

  const int tid = threadIdx.x;
  const int lane = tid & 63;
  const int w = tid >> 6;
  const int g = lane >> 4;
  const int R0 = blockIdx.x * 128;
  const int n = R0 >> 13;
  const int t0 = R0 & (TT - 1);

  if (tid == 0) scnt = 0;

  // ---- stage 128 rows into LDS (coalesced over t) ----
  {
    const float* xb = x + (size_t)n * (DD * TT) + t0;
    const int tt = tid & 127;
    const int dq = tid >> 7;  // 0..1
#pragma unroll
    for (int ch = 0; ch < 32; ++ch) {
      const int d = ch * 2 + dq;
      xs[tt][d] = xb[(size_t)d * TT + tt];
    }
  }

  // ---- per-thread B staging bases ----
  const int c16 = tid & 15;
  const ushort_t* kbsel = (w >= 2) ? kbl : kbh;
  const int kch = w & 1;
  const ushort_t* bq0 = kbsel + ((size_t)(0 * 16 + c16) * 64 + kch * 32 + g * 8);
  const ushort_t* bq1 = kbsel + ((size_t)(1 * 16 + c16) * 64 + kch * 32 + g * 8);
  const ushort_t* bq2 = kbsel + ((size_t)(2 * 16 + c16) * 64 + kch * 32 + g * 8);
  const ushort_t* bq3 = kbsel + ((size_t)(3 * 16 + c16) * 64 + kch * 32 + g * 8);

  // prologue: load + write phase 0
  {
    int4 r0 = *(const int4*)bq0;
    int4 r1 = *(const int4*)bq1;
    int4 r2 = *(const int4*)bq2;
    int4 r3 = *(const int4*)bq3;
    *(int4*)&Bl[0][(0 * 256 + tid) * 8] = r0;
    *(int4*)&Bl[0][(1 * 256 + tid) * 8] = r1;
    *(int4*)&Bl[0][(2 * 256 + tid) * 8] = r2;
    *(int4*)&Bl[0][(3 * 256 + tid) * 8] = r3;
  }
  __syncthreads();  // xs + phase-0 panel ready

  // ---- emit xf[row][d] transpose (for codesum + rescue) ----
  {
    const int row = tid >> 1;
    const int half = tid & 1;
    float4* dst = (float4*)(xf + (size_t)(R0 + row) * DD + half * 32);
#pragma unroll
    for (int j = 0; j < 8; ++j) {
      dst[j] = make_float4(xs[row][half * 32 + 4 * j], xs[row][half * 32 + 4 * j + 1],
                           xs[row][half * 32 + 4 * j + 2], xs[row][half * 32 + 4 * j + 3]);
    }
  }

  // ---- A-frag prep ----
  union FR { bf16x8 v; ushort_t u[8]; };
  bf16x8 ahi00, ahi01, ahi10, ahi11, alo00, alo01, alo10, alo11;
#define CVT(J, VAL)                                   \
  { const float fv = (VAL); const ushort_t hb = f2bf(fv); \
    hh.u[J] = hb; ll.u[J] = f2bf(__fsub_rn(fv, bf2f(hb))); }
#define APREP(M, C, HN, LN)                            \
  { const int rowl = w * 32 + (M)*16 + (lane & 15);    \
    const int d0 = (C)*32 + g * 8;                     \
    const float4 v0 = *(const float4*)&xs[rowl][d0];   \
    const float4 v1 = *(const float4*)&xs[rowl][d0 + 4]; \
    FR hh, ll;                                         \
    CVT(0, v0.x) CVT(1, v0.y) CVT(2, v0.z) CVT(3, v0.w) \
    CVT(4, v1.x) CVT(5, v1.y) CVT(6, v1.z) CVT(7, v1.w) \
    HN = hh.v; LN = ll.v; }
  APREP(0, 0, ahi00, alo00)
  APREP(0, 1, ahi01, alo01)
  APREP(1, 0, ahi10, alo10)
  APREP(1, 1, ahi11, alo11)

  const float FMAXV = 3.402823466e38f;
  float m1_0 = FMAXV, m1_1 = FMAXV, m1_2 = FMAXV, m1_3 = FMAXV;
  float m1_4 = FMAXV, m1_5 = FMAXV, m1_6 = FMAXV, m1_7 = FMAXV;
  float m2_0 = FMAXV, m2_1 = FMAXV, m2_2 = FMAXV, m2_3 = FMAXV;
  float m2_4 = FMAXV, m2_5 = FMAXV, m2_6 = FMAXV, m2_7 = FMAXV;
  int i1_0 = 0, i1_1 = 0, i1_2 = 0, i1_3 = 0;
  int i1_4 = 0, i1_5 = 0, i1_6 = 0, i1_7 = 0;

#define TRACK(S, V)                                                   \
  { const float dd = fmaf(-2.0f, (V), skc);                           \
    const bool lt = dd < m1_##S;                                      \
    m2_##S = fminf(m2_##S, lt ? m1_##S : dd);                         \
    m1_##S = lt ? dd : m1_##S;                                        \
    i1_##S = lt ? codeIdx : i1_##S; }

#define MFMA(A, B, C) __builtin_amdgcn_mfma_f32_16x16x32_bf16((A), (B), (C), 0, 0, 0)

#define TILE(TT_)                                                              \
  {                                                                            \
    const int codeBase = p * 64 + (TT_)*16;                                    \
    const bf16x8 bh0 = *(const bf16x8*)&Bl[pb][((TT_)*256 + 0 * 64 + lane) * 8]; \
    const bf16x8 bh1 = *(const bf16x8*)&Bl[pb][((TT_)*256 + 1 * 64 + lane) * 8]; \
    const bf16x8 bl0 = *(const bf16x8*)&Bl[pb][((TT_)*256 + 2 * 64 + lane) * 8]; \
    const bf16x8 bl1 = *(const bf16x8*)&Bl[pb][((TT_)*256 + 3 * 64 + lane) * 8]; \
    f32x4 acc0 = {0.f, 0.f, 0.f, 0.f}, acc1 = {0.f, 0.f, 0.f, 0.f};            \
    acc0 = MFMA(ahi00, bh0, acc0); acc0 = MFMA(ahi01, bh1, acc0);              \
    acc0 = MFMA(ahi00, bl0, acc0); acc0 = MFMA(ahi01, bl1, acc0);              \
    acc0 = MFMA(alo00, bh0, acc0); acc0 = MFMA(alo01, bh1, acc0);              \
    acc1 = MFMA(ahi10, bh0, acc1); acc1 = MFMA(ahi11, bh1, acc1);              \
    acc1 = MFMA(ahi10, bl0, acc1); acc1 = MFMA(ahi11, bl1, acc1);              \
    acc1 = MFMA(alo10, bh0, acc1); acc1 = MFMA(alo11, bh1, acc1);              \
    const float skc = sk[codeBase + (lane & 15)];                              \
    const int codeIdx = codeBase + (lane & 15);                                \
    TRACK(0, acc0[0]) TRACK(1, acc0[1]) TRACK(2, acc0[2]) TRACK(3, acc0[3])    \
    TRACK(4, acc1[0]) TRACK(5, acc1[1]) TRACK(6, acc1[2]) TRACK(7, acc1[3])    \
  }

  int4 rg0, rg1, rg2, rg3;
  for (int p = 0; p < 32; ++p) {
    const int pb = p & 1;
    if (p < 31) {  // issue next-panel loads (hide under MFMA)
      const size_t off = (size_t)(p + 1) * 4096;
      rg0 = *(const int4*)(bq0 + off);
      rg1 = *(const int4*)(bq1 + off);
      rg2 = *(const int4*)(bq2 + off);
      rg3 = *(const int4*)(bq3 + off);
    }
    TILE(0) TILE(1) TILE(2) TILE(3)
    __syncthreads();
    if (p < 31) {
      const int nb = pb ^ 1;
      *(int4*)&Bl[nb][(0 * 256 + tid) * 8] = rg0;
      *(int4*)&Bl[nb][(1 * 256 + tid) * 8] = rg1;
      *(int4*)&Bl[nb][(2 * 256 + tid) * 8] = rg2;
      *(int4*)&Bl[nb][(3 * 256 + tid) * 8] = rg3;
    }
    __syncthreads();
  }

  // ---- reduce across the 16 lanes of each lanegroup (codes) ----
#define REDSTEP(S, MASK)                                              \
  { const float o1 = __shfl_xor(m1_##S, MASK);                        \
    const int oi = __shfl_xor(i1_##S, MASK);                          \
    const float o2 = __shfl_xor(m2_##S, MASK);                        \
    const float hi2 = fmaxf(m1_##S, o1);                              \
    m2_##S = fminf(fminf(m2_##S, o2), hi2);                           \
    const bool tk = (o1 < m1_##S) || (o1 == m1_##S && oi < i1_##S);   \
    m1_##S = tk ? o1 : m1_##S;                                        \
    i1_##S = tk ? oi : i1_##S; }
#define RED(S) REDSTEP(S, 1) REDSTEP(S, 2) REDSTEP(S, 4) REDSTEP(S, 8)
  RED(0) RED(1) RED(2) RED(3) RED(4) RED(5) RED(6) RED(7)

  if ((lane & 15) == 0) {
#define WOUT(S, M, I)                                                   \
    { const int row = R0 + w * 32 + (M)*16 + g * 4 + (I);               \
      out_codes[row] = (float)i1_##S;                                   \
      if (m2_##S - m1_##S < TAUF) {                                     \
        const int pos = atomicAdd(&scnt, 1); slist[pos] = row;          \
      } else {                                                          \
        atomicAdd(&cnt_int[i1_##S], 1);                                 \
      } }
    WOUT(0, 0, 0) WOUT(1, 0, 1) WOUT(2, 0, 2) WOUT(3, 0, 3)
    WOUT(4, 1, 0) WOUT(5, 1, 1) WOUT(6, 1, 2) WOUT(7, 1, 3)
  }
  __syncthreads();
  if (tid == 0 && scnt > 0) sbase = atomicAdd(susp_cnt, scnt);
  __syncthreads();
  for (int i = tid; i < scnt; i += 256) susp_rows[sbase + i] = slist[i];
}

// ---------------- rescue: one WAVE per suspect row (r16/r17-validated) -------
// Counts its rows into cnt_int (pattern validated in r18/r19).
__global__ __launch_bounds__(256) void vq_rescue(
    const float* __restrict__ xf, const float* __restrict__ k,
    const float* __restrict__ sk, const int* __restrict__ susp_cnt,
    const int* __restrict__ susp_rows, float* __restrict__ out_codes,
    int* __restrict__ cnt_int) {
  __shared__ float xs[4][64];
  const int lane = threadIdx.x & 63;
  const int wv = threadIdx.x >> 6;
  const int nsusp = *susp_cnt;
  const int nit = (nsusp + 8191) >> 13;   // uniform trip count (8192 rows/pass)

  for (int it = 0; it < nit; ++it) {
    const int si = it * 8192 + blockIdx.x * 4 + wv;
    const bool act = si < nsusp;
    int row = 0;
    if (act) {
      row = susp_rows[si];
      xs[wv][lane] = xf[(size_t)row * DD + lane];   // coalesced
    }
    __syncthreads();

    if (act) {
      // np's ||x||^2 replica fold (broadcast LDS reads)
      float sumx;
      {
        float rr[8];
#pragma unroll
        for (int j = 0; j < 8; ++j) rr[j] = SQ(xs[wv][j]);
#pragma unroll
        for (int i = 8; i < 64; i += 8) {
#pragma unroll
          for (int j = 0; j < 8; ++j) rr[j] = __fadd_rn(rr[j], SQ(xs[wv][i + j]));
        }
        sumx = __fadd_rn(
            __fadd_rn(__fadd_rn(rr[0], rr[1]), __fadd_rn(rr[2], rr[3])),
            __fadd_rn(__fadd_rn(rr[4], rr[5]), __fadd_rn(rr[6], rr[7])));
      }

      float best = 3.402823466e38f;
      int bidx = lane;
#pragma unroll 4
      for (int i = 0; i < 32; ++i) {
        const int c = lane + i * 64;
        const float4* kp = (const float4*)(k + (size_t)c * DD);
        float a = 0.f;
#pragma unroll
        for (int j = 0; j < 16; ++j) {
          const float4 kv = kp[j];
          a = fmaf(xs[wv][4 * j + 0], kv.x, a);
          a = fmaf(xs[wv][4 * j + 1], kv.y, a);
          a = fmaf(xs[wv][4 * j + 2], kv.z, a);
          a = fmaf(xs[wv][4 * j + 3], kv.w, a);
        }
        const float dd = __fadd_rn(__fsub_rn(sumx, __fmul_rn(2.0f, a)), sk[c]);
        if (dd < best) { best = dd; bidx = c; }   // strict < -> first in-lane
      }

      // 64-lane butterfly, tie -> lowest index (np.argmin)
#pragma unroll
      for (int off = 1; off <= 32; off <<= 1) {
        const float ov = __shfl_xor(best, off);
        const int oi = __shfl_xor(bidx, off);
        if (ov < best || (ov == best && oi < bidx)) { best = ov; bidx = oi; }
      }
      if (lane == 0) {
        out_codes[row] = (float)bidx;
        atomicAdd(&cnt_int[bidx], 1);
      }
    }
    __syncthreads();
  }
}

// ---------------- bucket build: scan -> scatter packed entries ----------------
__global__ __launch_bounds__(256) void vq_scan(const int* __restrict__ cnt_int,
                                               int* __restrict__ cursor) {
  __shared__ int sm[256];
  const int t = threadIdx.x;
  int v[8];
  int tot = 0;
#pragma unroll
  for (int j = 0; j < 8; ++j) { v[j] = cnt_int[t * 8 + j]; tot += v[j]; }
  sm[t] = tot;
  __syncthreads();
  int val = tot;
  for (int off = 1; off < 256; off <<= 1) {
    const int add = (t >= off) ? sm[t - off] : 0;
    __syncthreads();
    val += add;
    sm[t] = val;
    __syncthreads();
  }
  int base = val - tot;  // exclusive
#pragma unroll
  for (int j = 0; j < 8; ++j) { cursor[t * 8 + j] = base; base += v[j]; }
}

// bucket entry = (code << 16) | row  (code < 2048, row < 65536)
__global__ __launch_bounds__(256) void vq_scatteridx(
    const float* __restrict__ codes_f, int* __restrict__ cursor,
    unsigned* __restrict__ bucket) {
  const int row = blockIdx.x * 256 + threadIdx.x;
  const int code = (int)codes_f[row];
  const int pos = atomicAdd(&cursor[code], 1);
  bucket[pos] = ((unsigned)code << 16) | (unsigned)row;
}

// ---------------- segmented sum: uniform 64-entry chunks per wave ----------
__global__ __launch_bounds__(256) void vq_codesum(
    const float* __restrict__ xf, const unsigned* __restrict__ bucket,
    float* __restrict__ out_ksum) {
  __shared__ unsigned sh[4][64];
  const int lane = threadIdx.x & 63;   // d
  const int wv = threadIdx.x >> 6;
  const int base = (blockIdx.x * 4 + wv) * 64;

  sh[wv][lane] = bucket[base + lane];
  __syncthreads();

  float acc = 0.f;
  int cur = (int)(sh[wv][0] >> 16);
#pragma unroll
  for (int b = 0; b < 8; ++b) {
    float xv[8];
    int cd[8];
#pragma unroll
    for (int j = 0; j < 8; ++j) {
      const unsigned p = sh[wv][b * 8 + j];
      cd[j] = (int)(p >> 16);
      xv[j] = xf[(size_t)(p & 0xFFFFu) * DD + lane];   // coalesced 256B
    }
#pragma unroll
    for (int j = 0; j < 8; ++j) {
      if (cd[j] != cur) {            // wave-uniform branch
        atomicAdd(&out_ksum[(size_t)cur * DD + lane], acc);
        acc = 0.f;
        cur = cd[j];
      }
      acc = __fadd_rn(acc, xv[j]);
    }
  }
  atomicAdd(&out_ksum[(size_t)cur * DD + lane], acc);
}

// ---------------- epilogue: pure streaming (no atomics) ----------------
__global__ __launch_bounds__(256) void vq_epi(
    const float* __restrict__ x, const float* __restrict__ k,
    const float* __restrict__ codes_f, float* __restrict__ out_xd,
    float* __restrict__ partial) {
  const int lane = threadIdx.x & 63;
  const int q = threadIdx.x >> 6;
  const int row = blockIdx.x * 64 + lane;
  const int n = row >> 13;
  const int t = row & (TT - 1);
  const int d0 = blockIdx.y * 16 + q * 4;

  const int code = (int)codes_f[row];

  const float* xp = x + (size_t)n * (DD * TT) + t;
  float* xd_base = out_xd + (size_t)n * (DD * TT) + t;

  const float4 kq = ((const float4*)k)[(size_t)code * 16 + (d0 >> 2)];

  float csum = 0.f;
#pragma unroll
  for (int j = 0; j < 4; ++j) {
    const int d = d0 + j;
    const float xqv = (j == 0) ? kq.x : (j == 1) ? kq.y : (j == 2) ? kq.z : kq.w;
    const float xv = xp[(size_t)d * TT];
    const float diff = __fsub_rn(xqv, xv);
    xd_base[(size_t)d * TT] = __fadd_rn(xv, diff);
    csum = fmaf(diff, diff, csum);
  }

  __shared__ float cs[4];
#pragma unroll
  for (int off = 32; off >= 1; off >>= 1) csum += __shfl_xor(csum, off);
  if (lane == 0) cs[q] = csum;
  __syncthreads();
  if (threadIdx.x == 0) {
    partial[blockIdx.y * 1024 + blockIdx.x] = (cs[0] + cs[1]) + (cs[2] + cs[3]);
  }
}

// ---------------- finalize: commit reduce + EMA buffers + k_new ----------------
__global__ __launch_bounds__(256) void vq_finalize(
    const float* __restrict__ k, const float* __restrict__ k_sum,
    const float* __restrict__ k_elem, const int* __restrict__ cnt_int,
    const float* __restrict__ partial, float* __restrict__ out_commit,
    float* __restrict__ out_knew, float* __restrict__ out_ksum,
    float* __restrict__ out_kelem) {
  const int i = blockIdx.x * 256 + threadIdx.x;

  if (blockIdx.x == 0) {
    __shared__ float red[256];
    float s = 0.f;
#pragma unroll
    for (int j = 0; j < 16; ++j) s += partial[threadIdx.x * 16 + j];
    red[threadIdx.x] = s;
    __syncthreads();
    for (int off = 128; off >= 1; off >>= 1) {
      if (threadIdx.x < off) red[threadIdx.x] += red[threadIdx.x + off];
      __syncthreads();
    }
    if (threadIdx.x == 0) out_commit[0] = red[0] / 4194304.0f;
  }

  if (i < KK * DD) {
    const int c = i >> 6;
    const float cnt = (float)cnt_int[c];
    const float ke_n = __fadd_rn(__fmul_rn(0.99f, k_elem[c]), __fmul_rn(0.01f, cnt));
    const float s_raw = out_ksum[i];
    const float ks_n = __fadd_rn(__fmul_rn(0.99f, k_sum[i]), __fmul_rn(0.01f, s_raw));
    out_ksum[i] = ks_n;
    out_knew[i] = (ke_n >= 1.0f) ? (ks_n / ke_n) : k[i];
    if ((i & 63) == 0) out_kelem[c] = ke_n;
  }
}

extern "C" void kernel_launch(void* const* d_in, const int* in_sizes, int n_in,
                              void* d_out, int out_size, void* d_ws, size_t ws_size,
                              hipStream_t stream) {
  const float* x = (const float*)d_in[0];
  const float* k = (const float*)d_in[1];
  const float* k_sum = (const float*)d_in[2];
  const float* k_elem = (const float*)d_in[3];

  float* out = (float*)d_out;
  float* out_xd = out;                 // doubles as xf scratch until vq_epi
  float* out_codes = out + OFF_CODES;
  float* out_commit = out + OFF_COMMIT;
  float* out_knew = out + OFF_KNEW;
  float* out_ksum = out + OFF_KSUM;
  float* out_kelem = out + OFF_KELEM;

  // bf16-split k lives in the out_knew region (512 KB), 16B-aligned; the
  // <=12 B overhang into out_ksum is wiped by the out_ksum memset (enqueued
  // after argmin). knew itself is rewritten by vq_finalize at the very end.
  ushort_t* kbh = (ushort_t*)(((size_t)(out + OFF_KNEW) + 15) & ~(size_t)15);
  ushort_t* kbl = kbh + (size_t)KK * DD;

  char* ws = (char*)d_ws;
  float* sk = (float*)ws;                       // 8 KB
  int* cnt_int = (int*)(ws + 8192);             // 8 KB
  int* cursor = (int*)(ws + 16384);             // 8 KB
  float* partial = (float*)(ws + 24576);        // 16 KB
  unsigned* bucket = (unsigned*)(ws + 40960);   // 256 KB
  int* susp_cnt = cursor;                       // aliased: rescue precedes scan
  int* susp_rows = (int*)bucket;                // aliased: rescue precedes scatter

  hipMemsetAsync(cnt_int, 0, (size_t)KK * sizeof(int), stream);
  hipMemsetAsync(susp_cnt, 0, sizeof(int), stream);

  vq_prep<<<(KK + 255) / 256, 256, 0, stream>>>(k, sk);
  vq_kprep<<<(KK * DD) / 256, 256, 0, stream>>>(k, kbh, kbl);

  vq_argmin_mfma<<<NTROWS / 128, 256, 0, stream>>>(x, kbh, kbl, sk, out_codes,
                                                   out_xd, susp_cnt, susp_rows,
                                                   cnt_int);

  // zero the atomic accumulation target (also wipes kbl's 12 B overhang)
  hipMemsetAsync(out_ksum, 0, (size_t)KK * DD * sizeof(float), stream);

  vq_rescue<<<2048, 256, 0, stream>>>(out_xd, k, sk, susp_cnt, susp_rows,
                                      out_codes, cnt_int);

  vq_scan<<<1, 256, 0, stream>>>(cnt_int, cursor);
  vq_scatteridx<<<NTROWS / 256, 256, 0, stream>>>(out_codes, cursor, bucket);
  vq_codesum<<<NTROWS / 256, 256, 0, stream>>>(out_xd, bucket, out_ksum);

  dim3 epi_grid(NTROWS / 64, 4);
  vq_epi<<<epi_grid, 256, 0, stream>>>(x, k, out_codes, out_xd, partial);

  vq_finalize<<<(KK * DD + 255) / 256, 256, 0, stream>>>(
      k, k_sum, k_elem, cnt_int, partial, out_commit, out_knew, out_ksum,
      out_kelem);
}